// Round 15
// baseline (314.471 us; speedup 1.0000x reference)
//
#include <hip/hip_runtime.h>
#include <math.h>

#define N_GT 256
#define M_PR 1024
#define LG   91
#define TPB  256
#define CPT  4    // cols per thread (256 threads * 4 = 1024)

// f64 DPP min-reduce stage (validated CTRL/mask sequence from r8; masked
// lanes keep old -> fmin(mine,mine) identity). Value-only; wave-scoped.
#define DPPMIN(red, CTRL, RM, BM) do { \
    int _rh = __double2hiint(red), _rl = __double2loint(red); \
    int _oh = __builtin_amdgcn_update_dpp(_rh, _rh, CTRL, RM, BM, false); \
    int _ol = __builtin_amdgcn_update_dpp(_rl, _rl, CTRL, RM, BM, false); \
    (red) = fmin((red), __hiloint2double(_oh, _ol)); \
} while (0)

// ---------------------------------------------------------------------------
// Kernel 1: cost[i][j] = sqrt(|cgt_i - cpred_j|^2) + sum_l |lgt_i - lpred_j|
// F64=1 stores the f32 value widened to double (bit-identical semantics).
// Fused rowmin/rowarg (first-occurrence argmin) for the greedy init.
// ---------------------------------------------------------------------------
template<int F64>
__global__ __launch_bounds__(256) void cost_kernel(
    const float* __restrict__ cgt, const float* __restrict__ cpred,
    const float* __restrict__ lgt, const float* __restrict__ lpred,
    void* __restrict__ costout, float* __restrict__ rowmin, int* __restrict__ rowarg)
{
    __shared__ float sg[LG];
    __shared__ float gx, gy;
    __shared__ float wmin[4];
    __shared__ int   warg[4];
    const int i   = blockIdx.x;
    const int tid = threadIdx.x;
    if (tid < LG) sg[tid] = lgt[i * LG + tid];
    if (tid == 0) { gx = cgt[2 * i]; gy = cgt[2 * i + 1]; }
    __syncthreads();
    float bv = 1e30f; int bj = 0;
    for (int j = tid; j < M_PR; j += 256) {
        float dx = gx - cpred[2 * j];
        float dy = gy - cpred[2 * j + 1];
        float cd = sqrtf(dx * dx + dy * dy);
        const float* lp = lpred + j * LG;
        float s = 0.f;
        #pragma unroll 7
        for (int l = 0; l < LG; ++l) s += fabsf(sg[l] - lp[l]);
        float cv = cd + s;
        if (F64) ((double*)costout)[(size_t)i * M_PR + j] = (double)cv;
        else     ((float*) costout)[(size_t)i * M_PR + j] = cv;
        if (cv < bv) { bv = cv; bj = j; }
    }
    const int lane = tid & 63, wid = tid >> 6;
    #pragma unroll
    for (int off = 1; off < 64; off <<= 1) {
        float ov = __shfl_xor(bv, off, 64);
        int   oj = __shfl_xor(bj, off, 64);
        if (ov < bv || (ov == bv && oj < bj)) { bv = ov; bj = oj; }
    }
    if (lane == 0) { wmin[wid] = bv; warg[wid] = bj; }
    __syncthreads();
    if (tid == 0) {
        for (int w = 1; w < 4; ++w)
            if (wmin[w] < bv || (wmin[w] == bv && warg[w] < bj)) { bv = wmin[w]; bj = warg[w]; }
        rowmin[i] = bv; rowarg[i] = bj;
    }
}

// ---------------------------------------------------------------------------
// Kernel 2: JV LSA (r8..r14-validated trace: greedy claim u=rowmin, v=0,
// then exact Dijkstra per unmatched row in ascending row order).
// r15 = r14 + speculative 4-candidate row prefetch: after the barrier the 4
// wave records (val, col|way, p[cand]) are visible; the next row is one of
// the 4 candidates' p values, so all 4 rows (each thread's own 32B slice)
// and all 4 u[] entries are loaded IMMEDIATELY, the merge compare-tree runs
// under that latency, and the winner's cd/ui are picked by a 2-level f64
// select tree (static indexing). The loop-top row load is gone; its latency
// hides under merge + next-iter settle/tournament. Values selected are
// bit-identical to what the removed load would fetch.
// Output (f32): [0..255]=row, [256..511]=col, [512]=cost.
// ---------------------------------------------------------------------------
template<int F64>
__global__ __launch_bounds__(256) void lsa_kernel(
    const void* __restrict__ costv,
    const float* __restrict__ rowmin, const int* __restrict__ rowarg,
    const float* __restrict__ cgt, const float* __restrict__ cpred,
    float* __restrict__ out)
{
    __shared__ double u[N_GT + 1];
    __shared__ double markD_lds[M_PR + 1];
    __shared__ double vsave_lds[M_PR + 1];
    __shared__ int    p[M_PR + 1];
    __shared__ int    pmin[M_PR + 1];
    __shared__ int    way[M_PR + 1];
    __shared__ int    pathbuf[N_GT + 8];
    __shared__ int    pathlen_s;
    __shared__ int    freeA[N_GT];
    __shared__ int    colarr[N_GT];
    __shared__ double2 wb[2][4];          // parity-double-buffered wave bests
    __shared__ int    wcnt[4];

    const int tid  = threadIdx.x;
    const int lane = tid & 63;
    const int wid  = tid >> 6;
    const double NEGINF = -__builtin_inf();
    const double INFD   =  __builtin_inf();

    double v[CPT], A[CPT];
    int    bw[CPT];

    const int colbase = tid * CPT;        // 0-based first owned col

    for (int j = tid; j <= M_PR; j += TPB) { p[j] = 0; pmin[j] = 0x7FFFFFFF; }
    colarr[tid] = 0;
    if (tid == 0) u[0] = 0.0;
    #pragma unroll
    for (int k = 0; k < CPT; ++k) { v[k] = 0.0; bw[k] = 0; }
    __syncthreads();

    // ---- greedy claim: row -> its argmin col, smallest row wins ----
    u[tid + 1] = (double)rowmin[tid];
    atomicMin(&pmin[rowarg[tid] + 1], tid + 1);
    __syncthreads();
    for (int j = tid + 1; j <= M_PR; j += TPB)
        p[j] = (pmin[j] == 0x7FFFFFFF) ? 0 : pmin[j];
    // free-row list (ascending row order), cross-wave ordered compaction
    {
        bool um = (pmin[rowarg[tid] + 1] != tid + 1);
        unsigned long long mask = __ballot(um);
        int local = __popcll(mask & ((1ull << lane) - 1ull));
        if (lane == 0) wcnt[wid] = __popcll(mask);
        __syncthreads();
        int base = 0;
        for (int w = 0; w < wid; ++w) base += wcnt[w];
        if (um) freeA[base + local] = tid + 1;       // 1-based row
        __syncthreads();
    }
    const int nfree = wcnt[0] + wcnt[1] + wcnt[2] + wcnt[3];

    int par = 0;
    // ---- shortest augmenting path per free row ----
    for (int t = 0; t < nfree; ++t) {
        const int i = freeA[t];
        #pragma unroll
        for (int k = 0; k < CPT; ++k) A[k] = 1e18;
        unsigned usedmask = 0u;
        double D  = 0.0;
        int    j0 = 0;

        // initial row load (row i) + ui
        double cd[CPT];
        if (F64) {
            const double2* rp = (const double2*)((const double*)costv
                                + (size_t)(i - 1) * M_PR + colbase);
            double2 t0v = rp[0], t1v = rp[1];
            cd[0] = t0v.x; cd[1] = t0v.y; cd[2] = t1v.x; cd[3] = t1v.y;
        } else {
            const float4* rp = (const float4*)((const float*)costv
                               + (size_t)(i - 1) * M_PR + colbase);
            float4 tv = rp[0];
            cd[0] = (double)tv.x; cd[1] = (double)tv.y;
            cd[2] = (double)tv.z; cd[3] = (double)tv.w;
        }
        double ui = u[i];

        while (true) {
            // settle previous winner j0 (owner thread only)
            if (j0 > 0 && ((j0 - 1) >> 2) == tid) {
                const int okk = (j0 - 1) & 3;
                markD_lds[j0] = D;
                #pragma unroll
                for (int k = 0; k < CPT; ++k) {
                    if (k == okk) {
                        vsave_lds[j0] = v[k];
                        v[k] = NEGINF;          // cur = +inf henceforth
                        A[k] = INFD;            // never a candidate again
                        usedmask |= (1u << k);
                    }
                }
            }

            // old-A tournament (4 entries)
            double   bAo  = INFD;
            unsigned bcwo = 0xFFFFFFFFu;
            #pragma unroll
            for (int k = 0; k < CPT; ++k) {
                unsigned cwk = ((unsigned)(colbase + k + 1) << 11) | (unsigned)bw[k];
                bool tk = A[k] < bAo;           // strict: smallest k kept on tie
                bAo  = tk ? A[k] : bAo;
                bcwo = tk ? cwk  : bcwo;
            }

            // vb = v + base2; cur = cd - vb (uniform formula, r13-validated)
            double base2 = ui - D;
            double vb[CPT];
            #pragma unroll
            for (int k = 0; k < CPT; ++k) vb[k] = v[k] + base2;

            double bAc = INFD; int bkc = 0;
            #pragma unroll
            for (int k = 0; k < CPT; ++k) {
                double cur = cd[k] - vb[k];
                bool upd = (cur < A[k]);        // settled: cur=+inf -> false
                A[k]  = upd ? cur : A[k];
                bw[k] = upd ? j0  : bw[k];
                bool tk = upd && (cur < bAc);
                bAc = tk ? cur : bAc;
                bkc = tk ? k   : bkc;
            }
            // merge: prefer old candidate on exact (value, col) tie
            int      colc = colbase + bkc + 1;
            unsigned cwc  = ((unsigned)colc << 11) | (unsigned)j0;
            int      colo = (int)(bcwo >> 11);
            bool tc = (bAc < bAo) || (bAc == bAo && colc < colo);
            double   bA  = tc ? bAc : bAo;
            unsigned bcw = tc ? cwc : bcwo;

            // per-lane p-prefetch of MY best col (p invariant inside search)
            int mycol = (int)(bcw >> 11);
            int pf = p[(mycol > M_PR) ? 0 : mycol];

            // intra-wave value-only DPP min reduce -> lane 63
            double red = bA;
            DPPMIN(red, 0x111, 0xf, 0xf);       // row_shr:1
            DPPMIN(red, 0x112, 0xf, 0xf);       // row_shr:2
            DPPMIN(red, 0x114, 0xf, 0xe);       // row_shr:4
            DPPMIN(red, 0x118, 0xf, 0xc);       // row_shr:8
            DPPMIN(red, 0x142, 0xa, 0xf);       // row_bcast:15
            DPPMIN(red, 0x143, 0xc, 0xf);       // row_bcast:31
            double Dw = __hiloint2double(
                __builtin_amdgcn_readlane(__double2hiint(red), 63),
                __builtin_amdgcn_readlane(__double2loint(red), 63));
            unsigned long long mm = __ballot(bA == Dw);   // wave-scoped
            int wl = __builtin_ctzll(mm);                 // lowest lane = smallest col
            unsigned rcw = (unsigned)__builtin_amdgcn_readlane((int)bcw, wl);
            int      pfw = __builtin_amdgcn_readlane(pf, wl);
            if (lane == 0) {
                double2 rec;
                rec.x = Dw;
                rec.y = __hiloint2double((int)rcw, (int)pfw);
                wb[par][wid] = rec;
            }
            __syncthreads();
            // read the 4 wave records
            double2 r0 = wb[par][0], r1 = wb[par][1];
            double2 r2 = wb[par][2], r3 = wb[par][3];
            par ^= 1;
            int rp0 = __double2loint(r0.y), rp1 = __double2loint(r1.y);
            int rp2 = __double2loint(r2.y), rp3 = __double2loint(r3.y);

            // SPECULATIVE: issue all 4 candidate rows' loads (own 32B slice)
            // + the 4 u[] broadcast reads, BEFORE the merge compare tree.
            double n0[CPT], n1[CPT], n2[CPT], n3[CPT];
            if (F64) {
                const double* base = (const double*)costv;
                const double2* q0 = (const double2*)(base + (size_t)((rp0 > 0 ? rp0 : 1) - 1) * M_PR + colbase);
                const double2* q1 = (const double2*)(base + (size_t)((rp1 > 0 ? rp1 : 1) - 1) * M_PR + colbase);
                const double2* q2 = (const double2*)(base + (size_t)((rp2 > 0 ? rp2 : 1) - 1) * M_PR + colbase);
                const double2* q3 = (const double2*)(base + (size_t)((rp3 > 0 ? rp3 : 1) - 1) * M_PR + colbase);
                double2 a0 = q0[0], b0 = q0[1];
                double2 a1 = q1[0], b1 = q1[1];
                double2 a2 = q2[0], b2 = q2[1];
                double2 a3 = q3[0], b3 = q3[1];
                n0[0]=a0.x; n0[1]=a0.y; n0[2]=b0.x; n0[3]=b0.y;
                n1[0]=a1.x; n1[1]=a1.y; n1[2]=b1.x; n1[3]=b1.y;
                n2[0]=a2.x; n2[1]=a2.y; n2[2]=b2.x; n2[3]=b2.y;
                n3[0]=a3.x; n3[1]=a3.y; n3[2]=b3.x; n3[3]=b3.y;
            } else {
                const float* base = (const float*)costv;
                float4 a0 = *(const float4*)(base + (size_t)((rp0 > 0 ? rp0 : 1) - 1) * M_PR + colbase);
                float4 a1 = *(const float4*)(base + (size_t)((rp1 > 0 ? rp1 : 1) - 1) * M_PR + colbase);
                float4 a2 = *(const float4*)(base + (size_t)((rp2 > 0 ? rp2 : 1) - 1) * M_PR + colbase);
                float4 a3 = *(const float4*)(base + (size_t)((rp3 > 0 ? rp3 : 1) - 1) * M_PR + colbase);
                n0[0]=(double)a0.x; n0[1]=(double)a0.y; n0[2]=(double)a0.z; n0[3]=(double)a0.w;
                n1[0]=(double)a1.x; n1[1]=(double)a1.y; n1[2]=(double)a1.z; n1[3]=(double)a1.w;
                n2[0]=(double)a2.x; n2[1]=(double)a2.y; n2[2]=(double)a2.z; n2[3]=(double)a2.w;
                n3[0]=(double)a3.x; n3[1]=(double)a3.y; n3[2]=(double)a3.z; n3[3]=(double)a3.w;
            }
            double u0 = u[rp0 > 0 ? rp0 : 0], u1 = u[rp1 > 0 ? rp1 : 0];
            double u2 = u[rp2 > 0 ? rp2 : 0], u3 = u[rp3 > 0 ? rp3 : 0];

            // merge compare tree on (val, col); wave order == col-block order
            unsigned c0 = (unsigned)__double2hiint(r0.y), c1 = (unsigned)__double2hiint(r1.y);
            unsigned c2 = (unsigned)__double2hiint(r2.y), c3 = (unsigned)__double2hiint(r3.y);
            bool b01 = (r1.x < r0.x) || (r1.x == r0.x && (c1 >> 11) < (c0 >> 11));
            double   v01 = b01 ? r1.x : r0.x;
            unsigned w01 = b01 ? c1   : c0;
            int      p01 = b01 ? rp1  : rp0;
            int      s01 = b01 ? 1    : 0;
            bool b23 = (r3.x < r2.x) || (r3.x == r2.x && (c3 >> 11) < (c2 >> 11));
            double   v23 = b23 ? r3.x : r2.x;
            unsigned w23 = b23 ? c3   : c2;
            int      p23 = b23 ? rp3  : rp2;
            int      s23 = b23 ? 3    : 2;
            bool bf = (v23 < v01) || (v23 == v01 && (w23 >> 11) < (w01 >> 11));
            D            = bf ? v23 : v01;
            unsigned mcw = bf ? w23 : w01;
            int      mpf = bf ? p23 : p01;
            int      wsel = bf ? s23 : s01;

            int j1 = (int)(mcw >> 11);
            if (tid == 0) way[j1] = (int)(mcw & 2047u);
            j0 = j1;
            if (mpf == 0) break;                // reached a free column (uniform)

            // select winner's cd/ui (2-level static bit-tree, rule #20 safe)
            const bool ws1 = (wsel & 1) != 0, ws2 = (wsel & 2) != 0;
            #pragma unroll
            for (int k = 0; k < CPT; ++k) {
                double e01 = ws1 ? n1[k] : n0[k];
                double e23 = ws1 ? n3[k] : n2[k];
                cd[k] = ws2 ? e23 : e01;
            }
            {
                double e01 = ws1 ? u1 : u0;
                double e23 = ws1 ? u3 : u2;
                ui = ws2 ? e23 : e01;
            }
        }
        // ---- deferred dual flush (pre-augmentation p) ----
        if (tid == 0) u[i] += D;                // virtual col 0: markD = 0
        #pragma unroll
        for (int k = 0; k < CPT; ++k) {
            if ((usedmask >> k) & 1u) {
                const int col = colbase + k + 1;
                double adj = D - markD_lds[col];
                v[k] = vsave_lds[col] - adj;    // restore + adjust
                int r = p[col];                 // distinct rows -> distinct u addrs
                u[r] += adj;
            }
        }
        __syncthreads();
        // ---- augmentation: collect path, then parallel apply (old reads) ----
        if (tid == 0) {
            int L = 0, jj = j0;
            while (jj != 0) { pathbuf[L++] = jj; jj = way[jj]; }
            pathlen_s = L;
        }
        // prefetch next search's first row while tid 0 walks
        if (t + 1 < nfree) {
            int nr = freeA[t + 1];
            if (F64) {
                const double* nrow = (const double*)costv + (size_t)(nr - 1) * M_PR + colbase;
                double t0v = nrow[0];
                asm volatile("" :: "v"(t0v));
            } else {
                const float* nrow = (const float*)costv + (size_t)(nr - 1) * M_PR + colbase;
                float t0v = nrow[0];
                asm volatile("" :: "v"(t0v));
            }
        }
        __syncthreads();
        const int L = pathlen_s;                // L <= 257
        int d0 = -1, s0 = 0, d1 = -1, s1 = 0;
        { int tt = tid;       if (tt < L) { d0 = pathbuf[tt]; s0 = (tt == L-1) ? i : p[pathbuf[tt+1]]; } }
        { int tt = tid + 256; if (tt < L) { d1 = pathbuf[tt]; s1 = (tt == L-1) ? i : p[pathbuf[tt+1]]; } }
        __syncthreads();
        if (d0 >= 0) p[d0] = s0;
        if (d1 >= 0) p[d1] = s1;
        __syncthreads();
    }

    // ---- gather + outputs ----
    #pragma unroll
    for (int k = 0; k < CPT; ++k) {
        int j  = colbase + k + 1;
        int pr = p[j];
        if (pr > 0) colarr[pr - 1] = j - 1;
    }
    __syncthreads();

    out[tid]        = (float)tid;               // row = arange(256)
    out[N_GT + tid] = (float)colarr[tid];       // col
    if (tid < 64) {                             // cost sum by wave 0
        float s = 0.f;
        for (int idx = lane; idx < N_GT; idx += 64) {
            int c = colarr[idx];
            c = (c < 0) ? 0 : (c >= M_PR ? M_PR - 1 : c);
            float dx = cgt[2 * idx]     - cpred[2 * c];
            float dy = cgt[2 * idx + 1] - cpred[2 * c + 1];
            s += sqrtf(dx * dx + dy * dy);
        }
        #pragma unroll
        for (int off = 1; off < 64; off <<= 1) s += __shfl_xor(s, off, 64);
        if (lane == 0) out[2 * N_GT] = s;
    }
}

extern "C" void kernel_launch(void* const* d_in, const int* in_sizes, int n_in,
                              void* d_out, int out_size, void* d_ws, size_t ws_size,
                              hipStream_t stream)
{
    const float* cgt   = (const float*)d_in[0];   // (256, 2)
    const float* cpred = (const float*)d_in[1];   // (1024, 2)
    const float* lgt   = (const float*)d_in[2];   // (256, 91)
    const float* lpred = (const float*)d_in[3];   // (1024, 91)
    float* out  = (float*)d_out;                  // 513 floats

    char* ws = (char*)d_ws;
    const size_t mat64 = (size_t)N_GT * M_PR * 8;           // 2 MB
    const size_t mat32 = (size_t)N_GT * M_PR * 4;           // 1 MB

    if (ws_size >= mat64 + 4096) {
        void*  cost   = (void*)ws;
        float* rowmin = (float*)(ws + mat64);
        int*   rowarg = (int*)  (ws + mat64 + 1024);
        cost_kernel<1><<<N_GT, 256, 0, stream>>>(cgt, cpred, lgt, lpred, cost, rowmin, rowarg);
        lsa_kernel<1><<<1, 256, 0, stream>>>(cost, rowmin, rowarg, cgt, cpred, out);
    } else {
        void*  cost   = (void*)ws;
        float* rowmin = (float*)(ws + mat32);
        int*   rowarg = (int*)  (ws + mat32 + 1024);
        cost_kernel<0><<<N_GT, 256, 0, stream>>>(cgt, cpred, lgt, lpred, cost, rowmin, rowarg);
        lsa_kernel<0><<<1, 256, 0, stream>>>(cost, rowmin, rowarg, cgt, cpred, out);
    }
}

// Round 16
// 282.967 us; speedup vs baseline: 1.1113x; 1.1113x over previous
//
#include <hip/hip_runtime.h>
#include <math.h>

#define N_GT 256
#define M_PR 1024
#define LG   91
#define TPB  256
#define CPT  4    // cols per thread (256 threads * 4 = 1024)

// f64 DPP min-reduce stage (validated CTRL/mask sequence from r8; masked
// lanes keep old -> fmin(mine,mine) identity). Value-only; wave-scoped.
#define DPPMIN(red, CTRL, RM, BM) do { \
    int _rh = __double2hiint(red), _rl = __double2loint(red); \
    int _oh = __builtin_amdgcn_update_dpp(_rh, _rh, CTRL, RM, BM, false); \
    int _ol = __builtin_amdgcn_update_dpp(_rl, _rl, CTRL, RM, BM, false); \
    (red) = fmin((red), __hiloint2double(_oh, _ol)); \
} while (0)

// ---------------------------------------------------------------------------
// Kernel 1: cost[i][j] = sqrt(|cgt_i - cpred_j|^2) + sum_l |lgt_i - lpred_j|
// F64=1 stores the f32 value widened to double (bit-identical semantics).
// Fused rowmin/rowarg (first-occurrence argmin) for the greedy init.
// ---------------------------------------------------------------------------
template<int F64>
__global__ __launch_bounds__(256) void cost_kernel(
    const float* __restrict__ cgt, const float* __restrict__ cpred,
    const float* __restrict__ lgt, const float* __restrict__ lpred,
    void* __restrict__ costout, float* __restrict__ rowmin, int* __restrict__ rowarg)
{
    __shared__ float sg[LG];
    __shared__ float gx, gy;
    __shared__ float wmin[4];
    __shared__ int   warg[4];
    const int i   = blockIdx.x;
    const int tid = threadIdx.x;
    if (tid < LG) sg[tid] = lgt[i * LG + tid];
    if (tid == 0) { gx = cgt[2 * i]; gy = cgt[2 * i + 1]; }
    __syncthreads();
    float bv = 1e30f; int bj = 0;
    for (int j = tid; j < M_PR; j += 256) {
        float dx = gx - cpred[2 * j];
        float dy = gy - cpred[2 * j + 1];
        float cd = sqrtf(dx * dx + dy * dy);
        const float* lp = lpred + j * LG;
        float s = 0.f;
        #pragma unroll 7
        for (int l = 0; l < LG; ++l) s += fabsf(sg[l] - lp[l]);
        float cv = cd + s;
        if (F64) ((double*)costout)[(size_t)i * M_PR + j] = (double)cv;
        else     ((float*) costout)[(size_t)i * M_PR + j] = cv;
        if (cv < bv) { bv = cv; bj = j; }
    }
    const int lane = tid & 63, wid = tid >> 6;
    #pragma unroll
    for (int off = 1; off < 64; off <<= 1) {
        float ov = __shfl_xor(bv, off, 64);
        int   oj = __shfl_xor(bj, off, 64);
        if (ov < bv || (ov == bv && oj < bj)) { bv = ov; bj = oj; }
    }
    if (lane == 0) { wmin[wid] = bv; warg[wid] = bj; }
    __syncthreads();
    if (tid == 0) {
        for (int w = 1; w < 4; ++w)
            if (wmin[w] < bv || (wmin[w] == bv && warg[w] < bj)) { bv = wmin[w]; bj = warg[w]; }
        rowmin[i] = bv; rowarg[i] = bj;
    }
}

// ---------------------------------------------------------------------------
// Kernel 2: JV LSA (r8..r13-validated trace: greedy claim u=rowmin, v=0,
// then exact Dijkstra per unmatched row in ascending row order).
// r16 = exact revert to r14 (best known: lsa 264us): 4-wave scan (256
// threads, 4 cols/thread) -- single-wave was ISSUE-bound (~330 VALU
// instrs/step ~= 996cy); 4 waves quarter per-wave issue. Cross-wave reduce:
// per-wave DPP+ballot winner -> one double2 LDS record; ONE barrier/step
// with parity double-buffered wb[2][4]; broadcast-read + (val,col) merge
// (exact smallest-col tie-break; wave order == col-block order).
// r15's speculative 4-candidate prefetch REVERTED: +45 instrs/step of issue
// in an issue-bound kernel (264->296us regression; the loop-top load was
// already hidden). All f64 formulas identical to r13 (vb=v+base2, cur=cd-vb).
// Output (f32): [0..255]=row, [256..511]=col, [512]=cost.
// ---------------------------------------------------------------------------
template<int F64>
__global__ __launch_bounds__(256) void lsa_kernel(
    const void* __restrict__ costv,
    const float* __restrict__ rowmin, const int* __restrict__ rowarg,
    const float* __restrict__ cgt, const float* __restrict__ cpred,
    float* __restrict__ out)
{
    __shared__ double u[N_GT + 1];
    __shared__ double markD_lds[M_PR + 1];
    __shared__ double vsave_lds[M_PR + 1];
    __shared__ int    p[M_PR + 1];
    __shared__ int    pmin[M_PR + 1];
    __shared__ int    way[M_PR + 1];
    __shared__ int    pathbuf[N_GT + 8];
    __shared__ int    pathlen_s;
    __shared__ int    freeA[N_GT];
    __shared__ int    colarr[N_GT];
    __shared__ double2 wb[2][4];          // parity-double-buffered wave bests
    __shared__ int    wcnt[4];

    const int tid  = threadIdx.x;
    const int lane = tid & 63;
    const int wid  = tid >> 6;
    const double NEGINF = -__builtin_inf();
    const double INFD   =  __builtin_inf();

    double v[CPT], A[CPT];
    int    bw[CPT];

    const int colbase = tid * CPT;        // 0-based first owned col

    for (int j = tid; j <= M_PR; j += TPB) { p[j] = 0; pmin[j] = 0x7FFFFFFF; }
    colarr[tid] = 0;
    if (tid == 0) u[0] = 0.0;
    #pragma unroll
    for (int k = 0; k < CPT; ++k) { v[k] = 0.0; bw[k] = 0; }
    __syncthreads();

    // ---- greedy claim: row -> its argmin col, smallest row wins ----
    u[tid + 1] = (double)rowmin[tid];
    atomicMin(&pmin[rowarg[tid] + 1], tid + 1);
    __syncthreads();
    for (int j = tid + 1; j <= M_PR; j += TPB)
        p[j] = (pmin[j] == 0x7FFFFFFF) ? 0 : pmin[j];
    // free-row list (ascending row order), cross-wave ordered compaction
    {
        bool um = (pmin[rowarg[tid] + 1] != tid + 1);
        unsigned long long mask = __ballot(um);
        int local = __popcll(mask & ((1ull << lane) - 1ull));
        if (lane == 0) wcnt[wid] = __popcll(mask);
        __syncthreads();
        int base = 0;
        for (int w = 0; w < wid; ++w) base += wcnt[w];
        if (um) freeA[base + local] = tid + 1;       // 1-based row
        __syncthreads();
    }
    const int nfree = wcnt[0] + wcnt[1] + wcnt[2] + wcnt[3];

    // warm the first search's row
    if (nfree > 0) {
        int nr = freeA[0];
        if (F64) {
            const double* nrow = (const double*)costv + (size_t)(nr - 1) * M_PR + colbase;
            double t0 = nrow[0];
            asm volatile("" :: "v"(t0));
        } else {
            const float* nrow = (const float*)costv + (size_t)(nr - 1) * M_PR + colbase;
            float t0 = nrow[0];
            asm volatile("" :: "v"(t0));
        }
    }

    int par = 0;
    // ---- shortest augmenting path per free row ----
    for (int t = 0; t < nfree; ++t) {
        const int i = freeA[t];
        #pragma unroll
        for (int k = 0; k < CPT; ++k) A[k] = 1e18;
        unsigned usedmask = 0u;
        double D  = 0.0;
        int    j0 = 0;
        int    i0 = i;
        while (true) {
            // row loads (issued first; settle/tournament/vb in shadow)
            double cd[CPT];
            if (F64) {
                const double2* rp = (const double2*)((const double*)costv
                                    + (size_t)(i0 - 1) * M_PR + colbase);
                double2 t0v = rp[0], t1v = rp[1];
                cd[0] = t0v.x; cd[1] = t0v.y; cd[2] = t1v.x; cd[3] = t1v.y;
            } else {
                const float4* rp = (const float4*)((const float*)costv
                                   + (size_t)(i0 - 1) * M_PR + colbase);
                float4 tv = rp[0];
                cd[0] = (double)tv.x; cd[1] = (double)tv.y;
                cd[2] = (double)tv.z; cd[3] = (double)tv.w;
            }
            double ui = u[i0];                  // LDS broadcast

            // settle previous winner j0 (owner thread only)
            if (j0 > 0 && ((j0 - 1) >> 2) == tid) {
                const int okk = (j0 - 1) & 3;
                markD_lds[j0] = D;
                #pragma unroll
                for (int k = 0; k < CPT; ++k) {
                    if (k == okk) {
                        vsave_lds[j0] = v[k];
                        v[k] = NEGINF;          // cur = +inf henceforth
                        A[k] = INFD;            // never a candidate again
                        usedmask |= (1u << k);
                    }
                }
            }

            // old-A tournament (4 entries, load-independent)
            double   bAo  = INFD;
            unsigned bcwo = 0xFFFFFFFFu;
            #pragma unroll
            for (int k = 0; k < CPT; ++k) {
                unsigned cwk = ((unsigned)(colbase + k + 1) << 11) | (unsigned)bw[k];
                bool tk = A[k] < bAo;           // strict: smallest k kept on tie
                bAo  = tk ? A[k] : bAo;
                bcwo = tk ? cwk  : bcwo;
            }

            // vb = v + base2 (load-independent); cur = cd - vb (uniform formula)
            double base2 = ui - D;
            double vb[CPT];
            #pragma unroll
            for (int k = 0; k < CPT; ++k) vb[k] = v[k] + base2;

            double bAc = INFD; int bkc = 0;
            #pragma unroll
            for (int k = 0; k < CPT; ++k) {
                double cur = cd[k] - vb[k];
                bool upd = (cur < A[k]);        // settled: cur=+inf -> false
                A[k]  = upd ? cur : A[k];
                bw[k] = upd ? j0  : bw[k];
                bool tk = upd && (cur < bAc);
                bAc = tk ? cur : bAc;
                bkc = tk ? k   : bkc;
            }
            // merge: prefer old candidate on exact (value, col) tie
            int      colc = colbase + bkc + 1;
            unsigned cwc  = ((unsigned)colc << 11) | (unsigned)j0;
            int      colo = (int)(bcwo >> 11);
            bool tc = (bAc < bAo) || (bAc == bAo && colc < colo);
            double   bA  = tc ? bAc : bAo;
            unsigned bcw = tc ? cwc : bcwo;

            // per-lane p-prefetch of MY best col (p invariant inside search)
            int mycol = (int)(bcw >> 11);
            int pf = p[(mycol > M_PR) ? 0 : mycol];

            // intra-wave value-only DPP min reduce -> lane 63
            double red = bA;
            DPPMIN(red, 0x111, 0xf, 0xf);       // row_shr:1
            DPPMIN(red, 0x112, 0xf, 0xf);       // row_shr:2
            DPPMIN(red, 0x114, 0xf, 0xe);       // row_shr:4
            DPPMIN(red, 0x118, 0xf, 0xc);       // row_shr:8
            DPPMIN(red, 0x142, 0xa, 0xf);       // row_bcast:15
            DPPMIN(red, 0x143, 0xc, 0xf);       // row_bcast:31
            double Dw = __hiloint2double(
                __builtin_amdgcn_readlane(__double2hiint(red), 63),
                __builtin_amdgcn_readlane(__double2loint(red), 63));
            unsigned long long mm = __ballot(bA == Dw);   // wave-scoped
            int wl = __builtin_ctzll(mm);                 // lowest lane = smallest col
            unsigned rcw = (unsigned)__builtin_amdgcn_readlane((int)bcw, wl);
            int      pfw = __builtin_amdgcn_readlane(pf, wl);
            if (lane == 0) {
                double2 rec;
                rec.x = Dw;
                rec.y = __hiloint2double((int)rcw, (int)pfw);
                wb[par][wid] = rec;
            }
            __syncthreads();
            // cross-wave merge (broadcast reads; (val,col) with smallest-col tie)
            double   bv_ = INFD;
            unsigned mcw = 0xFFFFFFFFu;
            int      mpf = 0;
            #pragma unroll
            for (int w = 0; w < 4; ++w) {
                double2 r = wb[par][w];
                unsigned rw  = (unsigned)__double2hiint(r.y);
                int      rpf = __double2loint(r.y);
                int      rcol = (int)(rw >> 11);
                bool b = (r.x < bv_) || (r.x == bv_ && rcol < (int)(mcw >> 11));
                bv_ = b ? r.x : bv_;
                mcw = b ? rw  : mcw;
                mpf = b ? rpf : mpf;
            }
            par ^= 1;
            D = bv_;
            int j1 = (int)(mcw >> 11);
            if (tid == 0) way[j1] = (int)(mcw & 2047u);
            j0 = j1;
            if (mpf == 0) break;                // reached a free column (uniform)
            i0 = mpf;
        }
        // ---- deferred dual flush (pre-augmentation p) ----
        if (tid == 0) u[i] += D;                // virtual col 0: markD = 0
        #pragma unroll
        for (int k = 0; k < CPT; ++k) {
            if ((usedmask >> k) & 1u) {
                const int col = colbase + k + 1;
                double adj = D - markD_lds[col];
                v[k] = vsave_lds[col] - adj;    // restore + adjust
                int r = p[col];                 // distinct rows -> distinct u addrs
                u[r] += adj;
            }
        }
        __syncthreads();
        // ---- augmentation: collect path, then parallel apply (old reads) ----
        if (tid == 0) {
            int L = 0, jj = j0;
            while (jj != 0) { pathbuf[L++] = jj; jj = way[jj]; }
            pathlen_s = L;
        }
        // prefetch next search's first row while tid 0 walks
        if (t + 1 < nfree) {
            int nr = freeA[t + 1];
            if (F64) {
                const double* nrow = (const double*)costv + (size_t)(nr - 1) * M_PR + colbase;
                double t0v = nrow[0];
                asm volatile("" :: "v"(t0v));
            } else {
                const float* nrow = (const float*)costv + (size_t)(nr - 1) * M_PR + colbase;
                float t0v = nrow[0];
                asm volatile("" :: "v"(t0v));
            }
        }
        __syncthreads();
        const int L = pathlen_s;                // L <= 257
        int d0 = -1, s0 = 0, d1 = -1, s1 = 0;
        { int tt = tid;       if (tt < L) { d0 = pathbuf[tt]; s0 = (tt == L-1) ? i : p[pathbuf[tt+1]]; } }
        { int tt = tid + 256; if (tt < L) { d1 = pathbuf[tt]; s1 = (tt == L-1) ? i : p[pathbuf[tt+1]]; } }
        __syncthreads();
        if (d0 >= 0) p[d0] = s0;
        if (d1 >= 0) p[d1] = s1;
        __syncthreads();
    }

    // ---- gather + outputs ----
    #pragma unroll
    for (int k = 0; k < CPT; ++k) {
        int j  = colbase + k + 1;
        int pr = p[j];
        if (pr > 0) colarr[pr - 1] = j - 1;
    }
    __syncthreads();

    out[tid]        = (float)tid;               // row = arange(256)
    out[N_GT + tid] = (float)colarr[tid];       // col
    if (tid < 64) {                             // cost sum by wave 0
        float s = 0.f;
        for (int idx = lane; idx < N_GT; idx += 64) {
            int c = colarr[idx];
            c = (c < 0) ? 0 : (c >= M_PR ? M_PR - 1 : c);
            float dx = cgt[2 * idx]     - cpred[2 * c];
            float dy = cgt[2 * idx + 1] - cpred[2 * c + 1];
            s += sqrtf(dx * dx + dy * dy);
        }
        #pragma unroll
        for (int off = 1; off < 64; off <<= 1) s += __shfl_xor(s, off, 64);
        if (lane == 0) out[2 * N_GT] = s;
    }
}

extern "C" void kernel_launch(void* const* d_in, const int* in_sizes, int n_in,
                              void* d_out, int out_size, void* d_ws, size_t ws_size,
                              hipStream_t stream)
{
    const float* cgt   = (const float*)d_in[0];   // (256, 2)
    const float* cpred = (const float*)d_in[1];   // (1024, 2)
    const float* lgt   = (const float*)d_in[2];   // (256, 91)
    const float* lpred = (const float*)d_in[3];   // (1024, 91)
    float* out  = (float*)d_out;                  // 513 floats

    char* ws = (char*)d_ws;
    const size_t mat64 = (size_t)N_GT * M_PR * 8;           // 2 MB
    const size_t mat32 = (size_t)N_GT * M_PR * 4;           // 1 MB

    if (ws_size >= mat64 + 4096) {
        void*  cost   = (void*)ws;
        float* rowmin = (float*)(ws + mat64);
        int*   rowarg = (int*)  (ws + mat64 + 1024);
        cost_kernel<1><<<N_GT, 256, 0, stream>>>(cgt, cpred, lgt, lpred, cost, rowmin, rowarg);
        lsa_kernel<1><<<1, 256, 0, stream>>>(cost, rowmin, rowarg, cgt, cpred, out);
    } else {
        void*  cost   = (void*)ws;
        float* rowmin = (float*)(ws + mat32);
        int*   rowarg = (int*)  (ws + mat32 + 1024);
        cost_kernel<0><<<N_GT, 256, 0, stream>>>(cgt, cpred, lgt, lpred, cost, rowmin, rowarg);
        lsa_kernel<0><<<1, 256, 0, stream>>>(cost, rowmin, rowarg, cgt, cpred, out);
    }
}